// Round 1
// baseline (493.701 us; speedup 1.0000x reference)
//
#include <hip/hip_runtime.h>

typedef __attribute__((ext_vector_type(8))) short short8;
typedef __attribute__((ext_vector_type(4))) float f32x4;

// Problem constants (fixed by setup_inputs)
constexpr int Nv   = 16384;   // vertices
constexpr int Ne   = 2048;    // hyperedges
constexpr int Np   = 262144;  // incidence pairs
constexpr int Cin  = 1024;
constexpr int Chid = 1024;
constexpr int Cout = 512;

__device__ __forceinline__ ushort f2bf(float f){
  unsigned u = __float_as_uint(f);
  u += 0x7FFFu + ((u >> 16) & 1u);   // RNE (finite inputs only)
  return (ushort)(u >> 16);
}
__device__ __forceinline__ float bf2f(ushort h){
  return __uint_as_float(((unsigned)h) << 16);
}

// ---------------- CSR build ----------------

__global__ void count_pairs(const int* __restrict__ pv, const int* __restrict__ pe,
                            int* __restrict__ vcnt, int* __restrict__ ecnt){
  int p = blockIdx.x * blockDim.x + threadIdx.x;
  if (p < Np){
    atomicAdd(&ecnt[pe[p]], 1);
    atomicAdd(&vcnt[pv[p]], 1);
  }
}

// exclusive scan, single block of 1024 threads, writes off[0..n]
__global__ void scan_excl(const int* __restrict__ cnt, int* __restrict__ off, int n){
  __shared__ int s[1024];
  __shared__ int carry_s;
  if (threadIdx.x == 0) carry_s = 0;
  __syncthreads();
  for (int base = 0; base < n; base += 1024){
    int i = base + (int)threadIdx.x;
    int v = (i < n) ? cnt[i] : 0;
    s[threadIdx.x] = v;
    __syncthreads();
    for (int d = 1; d < 1024; d <<= 1){
      int t = (threadIdx.x >= (unsigned)d) ? s[threadIdx.x - d] : 0;
      __syncthreads();
      s[threadIdx.x] += t;
      __syncthreads();
    }
    int incl = s[threadIdx.x];
    int carry = carry_s;
    if (i < n) off[i] = carry + incl - v;
    __syncthreads();
    if (threadIdx.x == 1023) carry_s = carry + s[1023];
    __syncthreads();
  }
  if (threadIdx.x == 0) off[n] = carry_s;
}

__global__ void fill_adj(const int* __restrict__ pv, const int* __restrict__ pe,
                         const int* __restrict__ eoff, int* __restrict__ efill, int* __restrict__ eadj,
                         const int* __restrict__ voff, int* __restrict__ vfill, int* __restrict__ vadj){
  int p = blockIdx.x * blockDim.x + threadIdx.x;
  if (p < Np){
    int e = pe[p], v = pv[p];
    int ie = atomicAdd(&efill[e], 1);
    eadj[eoff[e] + ie] = v;
    int iv = atomicAdd(&vfill[v], 1);
    vadj[voff[v] + iv] = e;
  }
}

// ---------------- dtype prep ----------------

__global__ void cvt_f32_bf16(const float* __restrict__ in, ushort* __restrict__ out, int n4){
  int i = blockIdx.x * blockDim.x + threadIdx.x;
  if (i < n4){
    float4 f = ((const float4*)in)[i];
    ushort4 o;
    o.x = f2bf(f.x); o.y = f2bf(f.y); o.z = f2bf(f.z); o.w = f2bf(f.w);
    ((ushort4*)out)[i] = o;
  }
}

// out[c][r] = bf16(in[r][c]); in: R x Ccols f32, R,Ccols multiples of 32
__global__ void transpose_cvt(const float* __restrict__ in, ushort* __restrict__ out,
                              int R, int Ccols){
  __shared__ float t[32][33];
  int c0 = blockIdx.x * 32, r0 = blockIdx.y * 32;
  int tx = threadIdx.x, ty = threadIdx.y;   // (32, 8)
  for (int j = 0; j < 32; j += 8)
    t[ty + j][tx] = in[(size_t)(r0 + ty + j) * Ccols + (c0 + tx)];
  __syncthreads();
  for (int j = 0; j < 32; j += 8)
    out[(size_t)(c0 + ty + j) * R + (r0 + tx)] = f2bf(t[tx][ty + j]);
}

// ---------------- bf16 MFMA GEMM: C = A * BT^T (+bias, relu) ----------------
// A: [M][K] bf16, BT: [N][K] bf16. 128x128 tile, BK=32, 4 waves of 64x64.

template<bool BIAS_RELU, bool OUT_BF16>
__global__ __launch_bounds__(256) void gemm_bt(
    const ushort* __restrict__ A, const ushort* __restrict__ BT,
    const float* __restrict__ bias, void* __restrict__ out,
    int M, int Nn, int K)
{
  __shared__ ushort As[128][40];   // +8 pad
  __shared__ ushort Bs[128][40];
  const int tid  = threadIdx.x;
  const int lane = tid & 63;
  const int wave = tid >> 6;
  const int wm = wave >> 1, wn = wave & 1;
  const int m0 = blockIdx.x * 128, n0 = blockIdx.y * 128;

  f32x4 acc[4][4] = {};

  const int r  = tid >> 1;          // 0..127 staging row
  const int c0 = (tid & 1) * 16;    // 0 or 16
  const int fr = lane & 15;
  const int kb = (lane >> 4) * 8;

  for (int k0 = 0; k0 < K; k0 += 32){
    __syncthreads();
    const ushort* pa = &A [(size_t)(m0 + r) * K + k0 + c0];
    const ushort* pb = &BT[(size_t)(n0 + r) * K + k0 + c0];
    short8 a0 = *(const short8*)pa;
    short8 a1 = *(const short8*)(pa + 8);
    short8 b0 = *(const short8*)pb;
    short8 b1 = *(const short8*)(pb + 8);
    *(short8*)&As[r][c0]     = a0;
    *(short8*)&As[r][c0 + 8] = a1;
    *(short8*)&Bs[r][c0]     = b0;
    *(short8*)&Bs[r][c0 + 8] = b1;
    __syncthreads();

    short8 af[4], bfv[4];
#pragma unroll
    for (int m = 0; m < 4; ++m) af[m]  = *(const short8*)&As[wm * 64 + m * 16 + fr][kb];
#pragma unroll
    for (int n = 0; n < 4; ++n) bfv[n] = *(const short8*)&Bs[wn * 64 + n * 16 + fr][kb];
#pragma unroll
    for (int m = 0; m < 4; ++m)
#pragma unroll
      for (int n = 0; n < 4; ++n)
        acc[m][n] = __builtin_amdgcn_mfma_f32_16x16x32_bf16(af[m], bfv[n], acc[m][n], 0, 0, 0);
  }

  // epilogue: D row = (lane>>4)*4 + i, col = lane&15
#pragma unroll
  for (int m = 0; m < 4; ++m){
#pragma unroll
    for (int n = 0; n < 4; ++n){
      int row0 = m0 + wm * 64 + m * 16 + ((lane >> 4) * 4);
      int col  = n0 + wn * 64 + n * 16 + (lane & 15);
      float bv = BIAS_RELU ? bias[col] : 0.0f;
#pragma unroll
      for (int i = 0; i < 4; ++i){
        int row = row0 + i;
        float v = acc[m][n][i];
        if (BIAS_RELU){ v += bv; v = v > 0.0f ? v : 0.0f; }
        if (OUT_BF16) ((ushort*)out)[(size_t)row * Nn + col] = f2bf(v);
        else          ((float*) out)[(size_t)row * Nn + col] = v;
      }
    }
  }
}

// ---------------- segment means (gather over CSR) ----------------

// one block per edge; block = C/4 threads; input bf16 rows; output bf16 or f32
template<int C, bool OUTF32>
__global__ void v2e_mean(const ushort* __restrict__ Xin, const int* __restrict__ eoff,
                         const int* __restrict__ eadj, void* __restrict__ out){
  __shared__ int vs[256];
  const int e = blockIdx.x;
  const int tid = threadIdx.x;
  const int c = tid * 4;
  const int beg = eoff[e], end = eoff[e + 1];
  float a0 = 0.f, a1 = 0.f, a2 = 0.f, a3 = 0.f;
  for (int base = beg; base < end; base += blockDim.x){
    int nchunk = min((int)blockDim.x, end - base);
    __syncthreads();
    if (tid < nchunk) vs[tid] = eadj[base + tid];
    __syncthreads();
    for (int j = 0; j < nchunk; ++j){
      int v = vs[j];
      ushort4 x = *(const ushort4*)&Xin[(size_t)v * C + c];
      a0 += bf2f(x.x); a1 += bf2f(x.y); a2 += bf2f(x.z); a3 += bf2f(x.w);
    }
  }
  float inv = 1.0f / (float)max(end - beg, 1);
  a0 *= inv; a1 *= inv; a2 *= inv; a3 *= inv;
  if (OUTF32){
    float4 o = {a0, a1, a2, a3};
    *(float4*)&((float*)out)[(size_t)e * C + c] = o;
  } else {
    ushort4 o = {f2bf(a0), f2bf(a1), f2bf(a2), f2bf(a3)};
    *(ushort4*)&((ushort*)out)[(size_t)e * C + c] = o;
  }
}

// one block per vertex; block = C/4 threads; input f32 edge rows
template<int C, bool BIASRELU, bool OUTBF16>
__global__ void e2v_mean(const float* __restrict__ Ein, const int* __restrict__ voff,
                         const int* __restrict__ vadj, const float* __restrict__ bias,
                         void* __restrict__ out){
  __shared__ int es[128];
  const int v = blockIdx.x;
  const int tid = threadIdx.x;
  const int c = tid * 4;
  const int beg = voff[v], end = voff[v + 1];
  float a0 = 0.f, a1 = 0.f, a2 = 0.f, a3 = 0.f;
  for (int base = beg; base < end; base += blockDim.x){
    int nchunk = min((int)blockDim.x, end - base);
    __syncthreads();
    if (tid < nchunk) es[tid] = vadj[base + tid];
    __syncthreads();
    for (int j = 0; j < nchunk; ++j){
      int e = es[j];
      float4 z = *(const float4*)&Ein[(size_t)e * C + c];
      a0 += z.x; a1 += z.y; a2 += z.z; a3 += z.w;
    }
  }
  float inv = 1.0f / (float)max(end - beg, 1);
  a0 *= inv; a1 *= inv; a2 *= inv; a3 *= inv;
  if (BIASRELU){
    a0 += bias[c];     a1 += bias[c + 1]; a2 += bias[c + 2]; a3 += bias[c + 3];
    a0 = a0 > 0.f ? a0 : 0.f;  a1 = a1 > 0.f ? a1 : 0.f;
    a2 = a2 > 0.f ? a2 : 0.f;  a3 = a3 > 0.f ? a3 : 0.f;
  }
  if (OUTBF16){
    ushort4 o = {f2bf(a0), f2bf(a1), f2bf(a2), f2bf(a3)};
    *(ushort4*)&((ushort*)out)[(size_t)v * C + c] = o;
  } else {
    float4 o = {a0, a1, a2, a3};
    *(float4*)&((float*)out)[(size_t)v * C + c] = o;
  }
}

// ---------------- launch ----------------

extern "C" void kernel_launch(void* const* d_in, const int* in_sizes, int n_in,
                              void* d_out, int out_size, void* d_ws, size_t ws_size,
                              hipStream_t stream){
  (void)in_sizes; (void)n_in; (void)out_size; (void)ws_size;
  const float* feat = (const float*)d_in[0];
  const int*   pv   = (const int*)d_in[1];
  const int*   pe   = (const int*)d_in[2];
  const float* W1   = (const float*)d_in[4];
  const float* b1   = (const float*)d_in[5];
  const float* W2   = (const float*)d_in[6];
  const float* b2   = (const float*)d_in[7];

  char* ws = (char*)d_ws;
  size_t off = 0;
  auto alloc = [&](size_t bytes) -> void* {
    void* p = ws + off;
    off += (bytes + 255) & ~(size_t)255;
    return p;
  };

  ushort* X1bf = (ushort*)alloc((size_t)Nv * Chid * 2);   // 32 MB: relu(F@W1+b1)
  ushort* Xe1  = (ushort*)alloc((size_t)Ne * Chid * 2);   // 4 MB: v2e mean of X1
  float*  Ze   = (float*) alloc((size_t)Ne * Cout * 4);   // 4 MB: Xe1 @ W2
  char*  regA  = (char*)  alloc((size_t)Nv * Cin  * 2);   // 32 MB, aliased:
  ushort* Abf  = (ushort*)regA;                           //   feature in bf16 (dead after GEMM1)
  ushort* X3bf = (ushort*)regA;                           //   relu(e2v(Ze)+b2)  (16 MB)
  float*  Xe2  = (float*)(regA + (size_t)Nv * Cout * 2);  //   v2e mean of X3    (4 MB)
  ushort* W1T  = (ushort*)alloc((size_t)Chid * Cin * 2);  // 2 MB
  ushort* W2T  = (ushort*)alloc((size_t)Cout * Chid * 2); // 1 MB

  int* zr     = (int*)alloc((size_t)(Ne + Nv + Ne + Nv) * 4);  // zeroed ints
  int* e_cnt  = zr;
  int* v_cnt  = zr + Ne;
  int* e_fill = zr + Ne + Nv;
  int* v_fill = zr + Ne + Nv + Ne;
  int* e_off  = (int*)alloc((size_t)(Ne + 1) * 4);
  int* v_off  = (int*)alloc((size_t)(Nv + 1) * 4);
  int* e_adj  = (int*)alloc((size_t)Np * 4);
  int* v_adj  = (int*)alloc((size_t)Np * 4);

  // --- CSR build ---
  hipMemsetAsync(zr, 0, (size_t)(Ne + Nv + Ne + Nv) * 4, stream);
  count_pairs<<<(Np + 255) / 256, 256, 0, stream>>>(pv, pe, v_cnt, e_cnt);
  scan_excl<<<1, 1024, 0, stream>>>(e_cnt, e_off, Ne);
  scan_excl<<<1, 1024, 0, stream>>>(v_cnt, v_off, Nv);
  fill_adj<<<(Np + 255) / 256, 256, 0, stream>>>(pv, pe, e_off, e_fill, e_adj,
                                                 v_off, v_fill, v_adj);

  // --- dtype prep ---
  cvt_f32_bf16<<<(Nv * Cin / 4 + 255) / 256, 256, 0, stream>>>(feat, Abf, Nv * Cin / 4);
  transpose_cvt<<<dim3(Chid / 32, Cin / 32), dim3(32, 8), 0, stream>>>(W1, W1T, Cin, Chid);
  transpose_cvt<<<dim3(Cout / 32, Chid / 32), dim3(32, 8), 0, stream>>>(W2, W2T, Chid, Cout);

  // --- layer 1 theta: X1 = relu(F @ W1 + b1) ---
  gemm_bt<true, true><<<dim3(Nv / 128, Chid / 128), 256, 0, stream>>>(
      Abf, W1T, b1, X1bf, Nv, Chid, Cin);

  // --- v2e mean (C=1024) ---
  v2e_mean<Chid, false><<<Ne, Chid / 4, 0, stream>>>(X1bf, e_off, e_adj, Xe1);

  // --- reordered theta2: Ze = Xe1 @ W2  (relu(v2v(X1)) == v2v(X1), W2 commutes through e2v) ---
  gemm_bt<false, false><<<dim3(Ne / 128, Cout / 128), 256, 0, stream>>>(
      Xe1, W2T, nullptr, Ze, Ne, Cout, Chid);

  // --- X3 = relu(e2v_mean(Ze) + b2) ---
  e2v_mean<Cout, true, true><<<Nv, Cout / 4, 0, stream>>>(Ze, v_off, v_adj, b2, X3bf);

  // --- layer 2 v2v ---
  v2e_mean<Cout, true><<<Ne, Cout / 4, 0, stream>>>(X3bf, e_off, e_adj, Xe2);
  e2v_mean<Cout, false, false><<<Nv, Cout / 4, 0, stream>>>(Xe2, v_off, v_adj, nullptr, (float*)d_out);
}

// Round 3
// 420.553 us; speedup vs baseline: 1.1739x; 1.1739x over previous
//
#include <hip/hip_runtime.h>

typedef __attribute__((ext_vector_type(8))) short short8;
typedef __attribute__((ext_vector_type(4))) float f32x4;

// Problem constants (fixed by setup_inputs)
constexpr int Nv   = 16384;   // vertices
constexpr int Ne   = 2048;    // hyperedges
constexpr int Np   = 262144;  // incidence pairs
constexpr int Cin  = 1024;
constexpr int Chid = 1024;
constexpr int Cout = 512;

__device__ __forceinline__ ushort f2bf(float f){
  unsigned u = __float_as_uint(f);
  u += 0x7FFFu + ((u >> 16) & 1u);   // RNE (finite inputs only)
  return (ushort)(u >> 16);
}
__device__ __forceinline__ float bf2f(ushort h){
  return __uint_as_float(((unsigned)h) << 16);
}

__device__ __forceinline__ void gload16(const void* g, void* lds){
  __builtin_amdgcn_global_load_lds(
      (const __attribute__((address_space(1))) void*)g,
      (__attribute__((address_space(3))) void*)lds, 16, 0, 0);
}

// ---------------- CSR build ----------------

__global__ void count_pairs(const int* __restrict__ pv, const int* __restrict__ pe,
                            int* __restrict__ vcnt, int* __restrict__ ecnt){
  int p = blockIdx.x * blockDim.x + threadIdx.x;
  if (p < Np){
    atomicAdd(&ecnt[pe[p]], 1);
    atomicAdd(&vcnt[pv[p]], 1);
  }
}

// exclusive scan via wave shfl, single block of 1024 threads, writes off[0..n]
__global__ void scan_excl(const int* __restrict__ cnt, int* __restrict__ off, int n){
  __shared__ int wsum[16];
  __shared__ int carry_s;
  const int lane = threadIdx.x & 63, wid = threadIdx.x >> 6;
  if (threadIdx.x == 0) carry_s = 0;
  __syncthreads();
  for (int base = 0; base < n; base += 1024){
    int i = base + (int)threadIdx.x;
    int v = (i < n) ? cnt[i] : 0;
    int s = v;
#pragma unroll
    for (int d = 1; d < 64; d <<= 1){
      int t = __shfl_up(s, d, 64);
      if (lane >= d) s += t;
    }
    if (lane == 63) wsum[wid] = s;
    __syncthreads();
    int wadd = 0;
#pragma unroll
    for (int w = 0; w < 16; ++w) if (w < wid) wadd += wsum[w];
    int carry = carry_s;
    if (i < n) off[i] = carry + wadd + s - v;
    __syncthreads();
    if (threadIdx.x == 1023) carry_s = carry + wadd + s;
    __syncthreads();
  }
  if (threadIdx.x == 0) off[n] = carry_s;
}

__global__ void fill_adj(const int* __restrict__ pv, const int* __restrict__ pe,
                         const int* __restrict__ eoff, int* __restrict__ efill, int* __restrict__ eadj,
                         const int* __restrict__ voff, int* __restrict__ vfill, int* __restrict__ vadj){
  int p = blockIdx.x * blockDim.x + threadIdx.x;
  if (p < Np){
    int e = pe[p], v = pv[p];
    int ie = atomicAdd(&efill[e], 1);
    eadj[eoff[e] + ie] = v;
    int iv = atomicAdd(&vfill[v], 1);
    vadj[voff[v] + iv] = e;
  }
}

// ---------------- dtype prep ----------------

__global__ void cvt_f32_bf16(const float* __restrict__ in, ushort* __restrict__ out, int n4){
  int i = blockIdx.x * blockDim.x + threadIdx.x;
  if (i < n4){
    float4 f = ((const float4*)in)[i];
    ushort4 o;
    o.x = f2bf(f.x); o.y = f2bf(f.y); o.z = f2bf(f.z); o.w = f2bf(f.w);
    ((ushort4*)out)[i] = o;
  }
}

// out[c][r] = bf16(in[r][c]); in: R x Ccols f32, R,Ccols multiples of 32
__global__ void transpose_cvt(const float* __restrict__ in, ushort* __restrict__ out,
                              int R, int Ccols){
  __shared__ float t[32][33];
  int c0 = blockIdx.x * 32, r0 = blockIdx.y * 32;
  int tx = threadIdx.x, ty = threadIdx.y;   // (32, 8)
  for (int j = 0; j < 32; j += 8)
    t[ty + j][tx] = in[(size_t)(r0 + ty + j) * Ccols + (c0 + tx)];
  __syncthreads();
  for (int j = 0; j < 32; j += 8)
    out[(size_t)(c0 + ty + j) * R + (r0 + tx)] = f2bf(t[tx][ty + j]);
}

// ---------------- bf16 MFMA GEMM: C = A * BT^T (+bias, relu) ----------------
// m97 structure: 128x128 tile, BK=32, global_load_lds width16, linear LDS.
// A: [M][K] bf16, BT: [N][K] bf16. 4 waves, each owns 64x64 of C.

template<bool BIAS_RELU, bool OUT_BF16>
__global__ __launch_bounds__(256) void gemm_bt(
    const ushort* __restrict__ A, const ushort* __restrict__ BT,
    const float* __restrict__ bias, void* __restrict__ out,
    int M, int Nn, int K)
{
  __shared__ ushort As[128 * 32];
  __shared__ ushort Bs[128 * 32];
  const int tid  = threadIdx.x;
  const int lane = tid & 63;
  const int wave = tid >> 6;
  const int wm = wave >> 1, wn = wave & 1;
  const int m0 = blockIdx.x * 128, n0 = blockIdx.y * 128;

  f32x4 acc[4][4] = {};

  // staging: thread t covers row t/4 (of 64), col-chunk (t%4)*8; two row-halves
  const int srow = tid >> 2;            // 0..63
  const int scol = (tid & 3) * 8;
  // wave-uniform LDS bases: wave w's 64 lanes fill rows w*16..w*16+15 (1024B)
  ushort* ldsA0 = &As[(wave * 16) * 32];
  ushort* ldsA1 = &As[(64 + wave * 16) * 32];
  ushort* ldsB0 = &Bs[(wave * 16) * 32];
  ushort* ldsB1 = &Bs[(64 + wave * 16) * 32];

  const int fr = lane & 15;             // fragment row within 16
  const int kb = (lane >> 4) * 8;       // k-offset (shorts)

  const size_t arow0 = (size_t)(m0 + srow) * K;
  const size_t arow1 = (size_t)(m0 + 64 + srow) * K;
  const size_t brow0 = (size_t)(n0 + srow) * K;
  const size_t brow1 = (size_t)(n0 + 64 + srow) * K;

  for (int k0 = 0; k0 < K; k0 += 32){
    __syncthreads();
    gload16(A  + arow0 + k0 + scol, ldsA0);
    gload16(A  + arow1 + k0 + scol, ldsA1);
    gload16(BT + brow0 + k0 + scol, ldsB0);
    gload16(BT + brow1 + k0 + scol, ldsB1);
    __syncthreads();   // compiler emits vmcnt(0) drain before barrier

    short8 af[4], bfv[4];
#pragma unroll
    for (int m = 0; m < 4; ++m) af[m]  = *(const short8*)&As[(wm * 64 + m * 16 + fr) * 32 + kb];
#pragma unroll
    for (int n = 0; n < 4; ++n) bfv[n] = *(const short8*)&Bs[(wn * 64 + n * 16 + fr) * 32 + kb];
#pragma unroll
    for (int m = 0; m < 4; ++m)
#pragma unroll
      for (int n = 0; n < 4; ++n)
        acc[m][n] = __builtin_amdgcn_mfma_f32_16x16x32_bf16(af[m], bfv[n], acc[m][n], 0, 0, 0);
  }

  // epilogue: D row = (lane>>4)*4 + i, col = lane&15
#pragma unroll
  for (int m = 0; m < 4; ++m){
#pragma unroll
    for (int n = 0; n < 4; ++n){
      int row0 = m0 + wm * 64 + m * 16 + ((lane >> 4) * 4);
      int col  = n0 + wn * 64 + n * 16 + (lane & 15);
      float bv = BIAS_RELU ? bias[col] : 0.0f;
#pragma unroll
      for (int i = 0; i < 4; ++i){
        int row = row0 + i;
        float v = acc[m][n][i];
        if (BIAS_RELU){ v += bv; v = v > 0.0f ? v : 0.0f; }
        if (OUT_BF16) ((ushort*)out)[(size_t)row * Nn + col] = f2bf(v);
        else          ((float*) out)[(size_t)row * Nn + col] = v;
      }
    }
  }
}

// ---------------- segment mean (gather over CSR), C=512, bf16 in ----------------

template<bool BIASRELU, bool OUTBF16>
__global__ void seg_mean512(const ushort* __restrict__ Xin, const int* __restrict__ off,
                            const int* __restrict__ adj, const float* __restrict__ bias,
                            void* __restrict__ out){
  __shared__ int idx[128];
  const int s = blockIdx.x;
  const int tid = threadIdx.x;   // 0..127
  const int c = tid * 4;
  const int beg = off[s], end = off[s + 1];
  float a0 = 0.f, a1 = 0.f, a2 = 0.f, a3 = 0.f;
  for (int base = beg; base < end; base += 128){
    int nch = min(128, end - base);
    __syncthreads();
    if (tid < nch) idx[tid] = adj[base + tid];
    __syncthreads();
#pragma unroll 4
    for (int j = 0; j < nch; ++j){
      const ushort4 x = *(const ushort4*)&Xin[(size_t)idx[j] * 512 + c];
      a0 += bf2f(x.x); a1 += bf2f(x.y); a2 += bf2f(x.z); a3 += bf2f(x.w);
    }
  }
  float inv = 1.0f / (float)max(end - beg, 1);
  a0 *= inv; a1 *= inv; a2 *= inv; a3 *= inv;
  if (BIASRELU){
    const float4 b = *(const float4*)&bias[c];
    a0 = fmaxf(a0 + b.x, 0.f); a1 = fmaxf(a1 + b.y, 0.f);
    a2 = fmaxf(a2 + b.z, 0.f); a3 = fmaxf(a3 + b.w, 0.f);
  }
  if (OUTBF16){
    ushort4 o = {f2bf(a0), f2bf(a1), f2bf(a2), f2bf(a3)};
    *(ushort4*)&((ushort*)out)[(size_t)s * 512 + c] = o;
  } else {
    float4 o = {a0, a1, a2, a3};
    *(float4*)&((float*)out)[(size_t)s * 512 + c] = o;
  }
}

// ---------------- launch ----------------

extern "C" void kernel_launch(void* const* d_in, const int* in_sizes, int n_in,
                              void* d_out, int out_size, void* d_ws, size_t ws_size,
                              hipStream_t stream){
  (void)in_sizes; (void)n_in; (void)out_size; (void)ws_size;
  const float* feat = (const float*)d_in[0];
  const int*   pv   = (const int*)d_in[1];
  const int*   pe   = (const int*)d_in[2];
  const float* W1   = (const float*)d_in[4];
  const float* b1   = (const float*)d_in[5];
  const float* W2   = (const float*)d_in[6];
  const float* b2   = (const float*)d_in[7];

  char* ws = (char*)d_ws;
  size_t off = 0;
  auto alloc = [&](size_t bytes) -> void* {
    void* p = ws + off;
    off += (bytes + 255) & ~(size_t)255;
    return p;
  };

  // buf0 (32MB): Abf (dead after GEMM1) -> then Y1 (16MB) | X3 (16MB)
  char* buf0 = (char*)alloc((size_t)Nv * Cin * 2);
  ushort* Abf = (ushort*)buf0;
  ushort* Y1  = (ushort*)buf0;                             // [Nv][Cout] bf16
  ushort* X3  = (ushort*)(buf0 + (size_t)Nv * Cout * 2);   // [Nv][Cout] bf16
  ushort* X1bf = (ushort*)alloc((size_t)Nv * Chid * 2);    // 32MB [Nv][Chid] bf16
  ushort* Ze   = (ushort*)alloc((size_t)Ne * Cout * 2);    // 2MB  [Ne][Cout] bf16
  ushort* Xe2  = (ushort*)alloc((size_t)Ne * Cout * 2);    // 2MB  [Ne][Cout] bf16
  ushort* W1T  = (ushort*)alloc((size_t)Chid * Cin * 2);   // 2MB
  ushort* W2T  = (ushort*)alloc((size_t)Cout * Chid * 2);  // 1MB

  int* zr     = (int*)alloc((size_t)(Ne + Nv + Ne + Nv) * 4);  // zeroed ints
  int* e_cnt  = zr;
  int* v_cnt  = zr + Ne;
  int* e_fill = zr + Ne + Nv;
  int* v_fill = zr + Ne + Nv + Ne;
  int* e_off  = (int*)alloc((size_t)(Ne + 1) * 4);
  int* v_off  = (int*)alloc((size_t)(Nv + 1) * 4);
  int* e_adj  = (int*)alloc((size_t)Np * 4);
  int* v_adj  = (int*)alloc((size_t)Np * 4);

  // --- CSR build ---
  hipMemsetAsync(zr, 0, (size_t)(Ne + Nv + Ne + Nv) * 4, stream);
  count_pairs<<<(Np + 255) / 256, 256, 0, stream>>>(pv, pe, v_cnt, e_cnt);
  scan_excl<<<1, 1024, 0, stream>>>(e_cnt, e_off, Ne);
  scan_excl<<<1, 1024, 0, stream>>>(v_cnt, v_off, Nv);
  fill_adj<<<(Np + 255) / 256, 256, 0, stream>>>(pv, pe, e_off, e_fill, e_adj,
                                                 v_off, v_fill, v_adj);

  // --- dtype prep ---
  cvt_f32_bf16<<<(Nv * Cin / 4 + 255) / 256, 256, 0, stream>>>(feat, Abf, Nv * Cin / 4);
  transpose_cvt<<<dim3(Chid / 32, Cin / 32), dim3(32, 8), 0, stream>>>(W1, W1T, Cin, Chid);
  transpose_cvt<<<dim3(Cout / 32, Chid / 32), dim3(32, 8), 0, stream>>>(W2, W2T, Chid, Cout);

  // --- X1 = relu(F @ W1 + b1)  [Nv][Chid] ---
  gemm_bt<true, true><<<dim3(Nv / 128, Chid / 128), 256, 0, stream>>>(
      Abf, W1T, b1, X1bf, Nv, Chid, Cin);

  // --- Y1 = X1 @ W2  [Nv][Cout]  (W2 commutes through both v2e and e2v means) ---
  gemm_bt<false, true><<<dim3(Nv / 128, Cout / 128), 256, 0, stream>>>(
      X1bf, W2T, nullptr, Y1, Nv, Cout, Chid);

  // --- Ze = v2e_mean(Y1)  [Ne][Cout] ---
  seg_mean512<false, true><<<Ne, 128, 0, stream>>>(Y1, e_off, e_adj, nullptr, Ze);

  // --- X3 = relu(e2v_mean(Ze) + b2)  [Nv][Cout] ---
  seg_mean512<true, true><<<Nv, 128, 0, stream>>>(Ze, v_off, v_adj, b2, X3);

  // --- layer-2 v2v: Xe2 = v2e_mean(X3); out = e2v_mean(Xe2) ---
  seg_mean512<false, true><<<Ne, 128, 0, stream>>>(X3, e_off, e_adj, nullptr, Xe2);
  seg_mean512<false, false><<<Nv, 128, 0, stream>>>(Xe2, v_off, v_adj, nullptr, (float*)d_out);
}

// Round 12
// 413.495 us; speedup vs baseline: 1.1940x; 1.0171x over previous
//
#include <hip/hip_runtime.h>

typedef __attribute__((ext_vector_type(8))) short short8;
typedef __attribute__((ext_vector_type(4))) float f32x4;

// Problem constants (fixed by setup_inputs)
constexpr int Nv   = 16384;   // vertices
constexpr int Ne   = 2048;    // hyperedges
constexpr int Np   = 262144;  // incidence pairs
constexpr int Cin  = 1024;
constexpr int Chid = 1024;
constexpr int Cout = 512;

__device__ __forceinline__ ushort f2bf(float f){
  unsigned u = __float_as_uint(f);
  u += 0x7FFFu + ((u >> 16) & 1u);   // RNE (finite inputs only)
  return (ushort)(u >> 16);
}
__device__ __forceinline__ float bf2f(ushort h){
  return __uint_as_float(((unsigned)h) << 16);
}

__device__ __forceinline__ void gload16(const void* g, void* lds){
  __builtin_amdgcn_global_load_lds(
      (const __attribute__((address_space(1))) void*)g,
      (__attribute__((address_space(3))) void*)lds, 16, 0, 0);
}

// ---------------- CSR build ----------------

__global__ void count_pairs(const int* __restrict__ pv, const int* __restrict__ pe,
                            int* __restrict__ vcnt, int* __restrict__ ecnt){
  int p = blockIdx.x * blockDim.x + threadIdx.x;
  if (p < Np){
    atomicAdd(&ecnt[pe[p]], 1);
    atomicAdd(&vcnt[pv[p]], 1);
  }
}

// exclusive scan via wave shfl, single block of 1024 threads, writes off[0..n]
__global__ void scan_excl(const int* __restrict__ cnt, int* __restrict__ off, int n){
  __shared__ int wsum[16];
  __shared__ int carry_s;
  const int lane = threadIdx.x & 63, wid = threadIdx.x >> 6;
  if (threadIdx.x == 0) carry_s = 0;
  __syncthreads();
  for (int base = 0; base < n; base += 1024){
    int i = base + (int)threadIdx.x;
    int v = (i < n) ? cnt[i] : 0;
    int s = v;
#pragma unroll
    for (int d = 1; d < 64; d <<= 1){
      int t = __shfl_up(s, d, 64);
      if (lane >= d) s += t;
    }
    if (lane == 63) wsum[wid] = s;
    __syncthreads();
    int wadd = 0;
#pragma unroll
    for (int w = 0; w < 16; ++w) if (w < wid) wadd += wsum[w];
    int carry = carry_s;
    if (i < n) off[i] = carry + wadd + s - v;
    __syncthreads();
    if (threadIdx.x == 1023) carry_s = carry + wadd + s;
    __syncthreads();
  }
  if (threadIdx.x == 0) off[n] = carry_s;
}

__global__ void fill_adj(const int* __restrict__ pv, const int* __restrict__ pe,
                         const int* __restrict__ eoff, int* __restrict__ efill, int* __restrict__ eadj,
                         const int* __restrict__ voff, int* __restrict__ vfill, int* __restrict__ vadj){
  int p = blockIdx.x * blockDim.x + threadIdx.x;
  if (p < Np){
    int e = pe[p], v = pv[p];
    int ie = atomicAdd(&efill[e], 1);
    eadj[eoff[e] + ie] = v;
    int iv = atomicAdd(&vfill[v], 1);
    vadj[voff[v] + iv] = e;
  }
}

// ---------------- dtype prep ----------------

__global__ void cvt_f32_bf16(const float* __restrict__ in, ushort* __restrict__ out, int n4){
  int i = blockIdx.x * blockDim.x + threadIdx.x;
  if (i < n4){
    float4 f = ((const float4*)in)[i];
    ushort4 o;
    o.x = f2bf(f.x); o.y = f2bf(f.y); o.z = f2bf(f.z); o.w = f2bf(f.w);
    ((ushort4*)out)[i] = o;
  }
}

// out[c][r] = bf16(in[r][c]); in: R x Ccols f32, R,Ccols multiples of 32
__global__ void transpose_cvt(const float* __restrict__ in, ushort* __restrict__ out,
                              int R, int Ccols){
  __shared__ float t[32][33];
  int c0 = blockIdx.x * 32, r0 = blockIdx.y * 32;
  int tx = threadIdx.x, ty = threadIdx.y;   // (32, 8)
  for (int j = 0; j < 32; j += 8)
    t[ty + j][tx] = in[(size_t)(r0 + ty + j) * Ccols + (c0 + tx)];
  __syncthreads();
  for (int j = 0; j < 32; j += 8)
    out[(size_t)(c0 + ty + j) * R + (r0 + tx)] = f2bf(t[tx][ty + j]);
}

// ---------------- bf16 MFMA GEMM: C = A * BT^T (+bias, relu) ----------------
// 128x128 tile, BK=32, global_load_lds width16, double-buffered prefetch
// (T3-minimum): stage next tile before compute, ONE barrier per K-step.
// A: [M][K] bf16, BT: [N][K] bf16. 4 waves, each owns 64x64 of C.

template<bool BIAS_RELU, bool OUT_BF16>
__global__ __launch_bounds__(256) void gemm_bt(
    const ushort* __restrict__ A, const ushort* __restrict__ BT,
    const float* __restrict__ bias, void* __restrict__ out,
    int M, int Nn, int K)
{
  __shared__ ushort As[2][128 * 32];
  __shared__ ushort Bs[2][128 * 32];
  const int tid  = threadIdx.x;
  const int lane = tid & 63;
  const int wave = tid >> 6;
  const int wm = wave >> 1, wn = wave & 1;
  const int m0 = blockIdx.x * 128, n0 = blockIdx.y * 128;

  f32x4 acc[4][4] = {};

  // staging: thread t covers row t/4 (0..63) + 64*half, col-chunk (t%4)*8
  const int srow = tid >> 2;
  const int scol = (tid & 3) * 8;
  const int ldsbase0 = (wave * 16) * 32;        // rows wave*16.., half 0
  const int ldsbase1 = (64 + wave * 16) * 32;   // half 1

  const int fr = lane & 15;             // fragment row within 16
  const int kb = (lane >> 4) * 8;       // k-offset (shorts)

  const size_t arow0 = (size_t)(m0 + srow) * K;
  const size_t arow1 = (size_t)(m0 + 64 + srow) * K;
  const size_t brow0 = (size_t)(n0 + srow) * K;
  const size_t brow1 = (size_t)(n0 + 64 + srow) * K;

  const int nt = K >> 5;   // K/32 tiles

  auto stage = [&](int b, int k0){
    gload16(A  + arow0 + k0 + scol, &As[b][ldsbase0]);
    gload16(A  + arow1 + k0 + scol, &As[b][ldsbase1]);
    gload16(BT + brow0 + k0 + scol, &Bs[b][ldsbase0]);
    gload16(BT + brow1 + k0 + scol, &Bs[b][ldsbase1]);
  };

  stage(0, 0);
  __syncthreads();           // vmcnt(0) drain: buf0 ready

  int cur = 0;
  for (int t = 0; t < nt; ++t){
    if (t + 1 < nt) stage(cur ^ 1, (t + 1) * 32);   // prefetch in flight across compute

    short8 af[4], bfv[4];
#pragma unroll
    for (int m = 0; m < 4; ++m) af[m]  = *(const short8*)&As[cur][(wm * 64 + m * 16 + fr) * 32 + kb];
#pragma unroll
    for (int n = 0; n < 4; ++n) bfv[n] = *(const short8*)&Bs[cur][(wn * 64 + n * 16 + fr) * 32 + kb];
#pragma unroll
    for (int m = 0; m < 4; ++m)
#pragma unroll
      for (int n = 0; n < 4; ++n)
        acc[m][n] = __builtin_amdgcn_mfma_f32_16x16x32_bf16(af[m], bfv[n], acc[m][n], 0, 0, 0);

    __syncthreads();         // drains prefetch (vmcnt 0) + all reads of buf[cur]
    cur ^= 1;
  }

  // epilogue: D row = (lane>>4)*4 + i, col = lane&15
#pragma unroll
  for (int m = 0; m < 4; ++m){
#pragma unroll
    for (int n = 0; n < 4; ++n){
      int row0 = m0 + wm * 64 + m * 16 + ((lane >> 4) * 4);
      int col  = n0 + wn * 64 + n * 16 + (lane & 15);
      float bv = BIAS_RELU ? bias[col] : 0.0f;
#pragma unroll
      for (int i = 0; i < 4; ++i){
        int row = row0 + i;
        float v = acc[m][n][i];
        if (BIAS_RELU){ v += bv; v = v > 0.0f ? v : 0.0f; }
        if (OUT_BF16) ((ushort*)out)[(size_t)row * Nn + col] = f2bf(v);
        else          ((float*) out)[(size_t)row * Nn + col] = v;
      }
    }
  }
}

// ---------------- segment mean (gather over CSR), C=512, bf16 in ----------------
// 4 waves/block; each wave reads whole 512-col rows (short8 = 16B/lane),
// waves stride the member list by 4, hand-unrolled x2 -> >=8 row-loads in
// flight per block. Cross-wave LDS reduce at the end.

template<bool BIASRELU, bool OUTBF16>
__global__ __launch_bounds__(256) void seg_mean512(
    const ushort* __restrict__ Xin, const int* __restrict__ off,
    const int* __restrict__ adj, const float* __restrict__ bias,
    void* __restrict__ out){
  __shared__ int idx[256];
  __shared__ float part[4][512];
  const int s = blockIdx.x;
  const int tid  = threadIdx.x;
  const int lane = tid & 63;
  const int wv   = tid >> 6;
  const int c0   = lane * 8;            // this lane's 8 columns
  const int beg = off[s], end = off[s + 1];

  float a0[8] = {}, a1[8] = {};

  for (int base = beg; base < end; base += 256){
    const int nch = min(256, end - base);
    __syncthreads();
    if (tid < nch) idx[tid] = adj[base + tid];
    __syncthreads();
    int j = wv;
    for (; j + 4 < nch; j += 8){
      short8 x0 = *(const short8*)&Xin[(size_t)idx[j]     * 512 + c0];
      short8 x1 = *(const short8*)&Xin[(size_t)idx[j + 4] * 512 + c0];
#pragma unroll
      for (int k = 0; k < 8; ++k){
        a0[k] += bf2f((ushort)x0[k]);
        a1[k] += bf2f((ushort)x1[k]);
      }
    }
    if (j < nch){
      short8 x0 = *(const short8*)&Xin[(size_t)idx[j] * 512 + c0];
#pragma unroll
      for (int k = 0; k < 8; ++k) a0[k] += bf2f((ushort)x0[k]);
    }
  }

  f32x4 p0 = {a0[0] + a1[0], a0[1] + a1[1], a0[2] + a1[2], a0[3] + a1[3]};
  f32x4 p1 = {a0[4] + a1[4], a0[5] + a1[5], a0[6] + a1[6], a0[7] + a1[7]};
  *(f32x4*)&part[wv][c0]     = p0;
  *(f32x4*)&part[wv][c0 + 4] = p1;
  __syncthreads();

  const float inv = 1.0f / (float)max(end - beg, 1);
  const int c = tid * 2;                // each thread finalizes 2 columns
  float r0 = (part[0][c]     + part[1][c]     + part[2][c]     + part[3][c])     * inv;
  float r1 = (part[0][c + 1] + part[1][c + 1] + part[2][c + 1] + part[3][c + 1]) * inv;
  if (BIASRELU){
    r0 = fmaxf(r0 + bias[c], 0.f);
    r1 = fmaxf(r1 + bias[c + 1], 0.f);
  }
  if (OUTBF16){
    ushort2 o = {f2bf(r0), f2bf(r1)};
    *(ushort2*)&((ushort*)out)[(size_t)s * 512 + c] = o;
  } else {
    float2 o = {r0, r1};
    *(float2*)&((float*)out)[(size_t)s * 512 + c] = o;
  }
}

// ---------------- launch ----------------

extern "C" void kernel_launch(void* const* d_in, const int* in_sizes, int n_in,
                              void* d_out, int out_size, void* d_ws, size_t ws_size,
                              hipStream_t stream){
  (void)in_sizes; (void)n_in; (void)out_size; (void)ws_size;
  const float* feat = (const float*)d_in[0];
  const int*   pv   = (const int*)d_in[1];
  const int*   pe   = (const int*)d_in[2];
  const float* W1   = (const float*)d_in[4];
  const float* b1   = (const float*)d_in[5];
  const float* W2   = (const float*)d_in[6];
  const float* b2   = (const float*)d_in[7];

  char* ws = (char*)d_ws;
  size_t off = 0;
  auto alloc = [&](size_t bytes) -> void* {
    void* p = ws + off;
    off += (bytes + 255) & ~(size_t)255;
    return p;
  };

  // buf0 (32MB): Abf (dead after GEMM1) -> then Y1 (16MB) | X3 (16MB)
  char* buf0 = (char*)alloc((size_t)Nv * Cin * 2);
  ushort* Abf = (ushort*)buf0;
  ushort* Y1  = (ushort*)buf0;                             // [Nv][Cout] bf16
  ushort* X3  = (ushort*)(buf0 + (size_t)Nv * Cout * 2);   // [Nv][Cout] bf16
  ushort* X1bf = (ushort*)alloc((size_t)Nv * Chid * 2);    // 32MB [Nv][Chid] bf16
  ushort* Ze   = (ushort*)alloc((size_t)Ne * Cout * 2);    // 2MB  [Ne][Cout] bf16
  ushort* Xe2  = (ushort*)alloc((size_t)Ne * Cout * 2);    // 2MB  [Ne][Cout] bf16
  ushort* W1T  = (ushort*)alloc((size_t)Chid * Cin * 2);   // 2MB
  ushort* W2T  = (ushort*)alloc((size_t)Cout * Chid * 2);  // 1MB

  int* zr     = (int*)alloc((size_t)(Ne + Nv + Ne + Nv) * 4);  // zeroed ints
  int* e_cnt  = zr;
  int* v_cnt  = zr + Ne;
  int* e_fill = zr + Ne + Nv;
  int* v_fill = zr + Ne + Nv + Ne;
  int* e_off  = (int*)alloc((size_t)(Ne + 1) * 4);
  int* v_off  = (int*)alloc((size_t)(Nv + 1) * 4);
  int* e_adj  = (int*)alloc((size_t)Np * 4);
  int* v_adj  = (int*)alloc((size_t)Np * 4);

  // --- CSR build ---
  hipMemsetAsync(zr, 0, (size_t)(Ne + Nv + Ne + Nv) * 4, stream);
  count_pairs<<<(Np + 255) / 256, 256, 0, stream>>>(pv, pe, v_cnt, e_cnt);
  scan_excl<<<1, 1024, 0, stream>>>(e_cnt, e_off, Ne);
  scan_excl<<<1, 1024, 0, stream>>>(v_cnt, v_off, Nv);
  fill_adj<<<(Np + 255) / 256, 256, 0, stream>>>(pv, pe, e_off, e_fill, e_adj,
                                                 v_off, v_fill, v_adj);

  // --- dtype prep ---
  cvt_f32_bf16<<<(Nv * Cin / 4 + 255) / 256, 256, 0, stream>>>(feat, Abf, Nv * Cin / 4);
  transpose_cvt<<<dim3(Chid / 32, Cin / 32), dim3(32, 8), 0, stream>>>(W1, W1T, Cin, Chid);
  transpose_cvt<<<dim3(Cout / 32, Chid / 32), dim3(32, 8), 0, stream>>>(W2, W2T, Chid, Cout);

  // --- X1 = relu(F @ W1 + b1)  [Nv][Chid] ---
  gemm_bt<true, true><<<dim3(Nv / 128, Chid / 128), 256, 0, stream>>>(
      Abf, W1T, b1, X1bf, Nv, Chid, Cin);

  // --- Y1 = X1 @ W2  [Nv][Cout]  (W2 commutes through both v2e and e2v means) ---
  gemm_bt<false, true><<<dim3(Nv / 128, Cout / 128), 256, 0, stream>>>(
      X1bf, W2T, nullptr, Y1, Nv, Cout, Chid);

  // --- Ze = v2e_mean(Y1)  [Ne][Cout] ---
  seg_mean512<false, true><<<Ne, 256, 0, stream>>>(Y1, e_off, e_adj, nullptr, Ze);

  // --- X3 = relu(e2v_mean(Ze) + b2)  [Nv][Cout] ---
  seg_mean512<true, true><<<Nv, 256, 0, stream>>>(Ze, v_off, v_adj, b2, X3);

  // --- layer-2 v2v: Xe2 = v2e_mean(X3); out = e2v_mean(Xe2) ---
  seg_mean512<false, true><<<Ne, 256, 0, stream>>>(X3, e_off, e_adj, nullptr, Xe2);
  seg_mean512<false, false><<<Nv, 256, 0, stream>>>(Xe2, v_off, v_adj, nullptr, (float*)d_out);
}